// Round 1
// baseline (1628.743 us; speedup 1.0000x reference)
//
#include <hip/hip_runtime.h>

#define B   512
#define T   256
#define BT  (512*256)

using short8  = __attribute__((ext_vector_type(8))) short;
using floatx4 = __attribute__((ext_vector_type(4))) float;

__device__ inline unsigned short f2bf(float f){
  unsigned int u = __float_as_uint(f);
  u += 0x7FFFu + ((u >> 16) & 1u);          // RNE
  return (unsigned short)(u >> 16);
}
__device__ inline float fast_sig(float x){
  return __builtin_amdgcn_rcpf(1.f + __expf(-x));
}
__device__ inline float fast_tanh(float x){
  return 1.f - 2.f * __builtin_amdgcn_rcpf(1.f + __expf(2.f * x));
}

// ---------------- kernel 1: int_all + static outputs ----------------
__global__ __launch_bounds__(256) void k_int(
    const float* __restrict__ in, const float* __restrict__ w1,
    const float* __restrict__ b1, const float* __restrict__ w3,
    const float* __restrict__ b3, const float* __restrict__ scw,
    float* __restrict__ out)
{
  __shared__ floatx4 lw[128];
  __shared__ float   l3[128];
  int tid = threadIdx.x;
  if(tid < 128){
    floatx4 v = { w1[tid*3+0], w1[tid*3+1], w1[tid*3+2], b1[tid] };
    lw[tid] = v; l3[tid] = w3[tid];
  }
  __syncthreads();
  int idx = blockIdx.x*256 + tid;
  int b = idx >> 8, t = idx & 255;
  const float* row = in + b*1792 + t*7;
  float x0 = row[3], x1 = row[4], x2 = row[5];
  float acc = 0.f;
  #pragma unroll 8
  for(int j=0;j<128;j++){
    floatx4 w = lw[j];
    float r = fmaxf(w.x*x0 + w.y*x1 + w.z*x2 + w.w, 0.f);
    acc += r * l3[j];
  }
  float v = fast_sig(acc + b3[0]) * scw[0];
  out[idx + BT]   = row[6];                  // HVAC_list
  out[idx + 3*BT] = (t < 8) ? 0.f : v;       // Int_list (also read by k_seq)
  if(t < 8){
    out[idx]        = row[0];                // TOut[:, :8] = T0
    out[idx + 2*BT] = 0.f;                   // Ext_list[:, :8] = 0
  }
}

// ---------------- kernel 2: persistent sequential recurrence ----------------
#define HROW 168   // h_lds row stride (ushort), 16B-aligned, conflict-friendly
#define EROW 72    // embed row stride (ushort)

__global__ __launch_bounds__(256,1) void k_seq(
    const float* __restrict__ in,
    const float* __restrict__ Wih,  const float* __restrict__ Whh,
    const float* __restrict__ bih,  const float* __restrict__ bhh,
    const float* __restrict__ fc1w, const float* __restrict__ fc1b,
    const float* __restrict__ fc2w, const float* __restrict__ fc2b,
    const float* __restrict__ zonew,
    float* __restrict__ out)
{
  __shared__ __align__(16) unsigned short h_lds[16*HROW];
  __shared__ __align__(16) unsigned short emb[16*EROW];
  __shared__ __align__(16) unsigned short zpad[8];
  __shared__ float gbuf[2*512];
  __shared__ float obuf[2*128];
  __shared__ float toutl[2*256];
  __shared__ float E_l[2];

  const int tid  = threadIdx.x;
  const int wv   = tid >> 6;
  const int ln   = tid & 63;
  const int l15  = ln & 15;
  const int quad = ln >> 4;
  const int bb   = blockIdx.x;          // batches 2*bb, 2*bb+1

  // ---- init LDS ----
  for(int p = tid; p < 16*HROW; p += 256) h_lds[p] = 0;
  for(int p = tid; p < 16*EROW; p += 256) emb[p]   = 0;
  if(tid < 8) zpad[tid] = 0;
  { int m = tid >> 7, j = tid & 127; h_lds[m*HROW + j] = 0x3F80; }  // h = 1.0
  if(tid < 16){ int m = tid>>3, t = tid&7; toutl[m*256 + t] = in[(2*bb+m)*1792 + t*7]; }
  if(tid < 2){ E_l[tid] = in[(2*bb+tid)*1792 + 8*7]; }             // E = T0[:,8]

  // ---- weight fragments into VGPRs ----
  // gate rows for this wave: n = 128*gate + 32*wv + 16*s + l15  (tile t = gate*2+s)
  short8 wfr[8][5];
  #pragma unroll
  for(int t=0;t<8;t++){
    int n = 128*(t>>1) + 32*wv + 16*(t&1) + l15;
    #pragma unroll
    for(int q=0;q<5;q++){
      short8 f;
      #pragma unroll
      for(int j=0;j<8;j++){
        float v;
        if(q < 4){ int k = q*32 + quad*8 + j; v = Whh[n*128 + k]; }
        else     { int kk = quad*8 + j;       v = (kk < 5) ? Wih[n*5 + kk] : 0.f; }
        f[j] = (short)f2bf(v);
      }
      wfr[t][q] = f;
    }
  }
  short8 ffr[2][4];
  #pragma unroll
  for(int t=0;t<2;t++){
    int n = 32*wv + 16*t + l15;
    #pragma unroll
    for(int q=0;q<4;q++){
      short8 f;
      #pragma unroll
      for(int j=0;j<8;j++) f[j] = (short)f2bf(fc1w[n*128 + q*32 + quad*8 + j]);
      ffr[t][q] = f;
    }
  }

  // ---- per-lane persistent scalars ----
  const int uj = tid & 127;                       // hidden index this lane updates
  const float bi_i = bih[uj]      + bhh[uj];
  const float bi_f = bih[128+uj]  + bhh[128+uj];
  const float bi_g = bih[256+uj]  + bhh[256+uj];
  const float bi_o = bih[384+uj]  + bhh[384+uj];
  float c = 1.f;
  const float fb0 = fc1b[32*wv + l15];
  const float fb1 = fc1b[32*wv + 16 + l15];
  const float fw0 = fc2w[ln];
  const float fw1 = fc2w[64+ln];
  const float fc2b0 = fc2b[0];
  const float zw    = zonew[0];
  const int hoff = l15*HROW + quad*8;             // A-frag base (element idx)
  __syncthreads();

  #pragma unroll 1
  for(int i=8;i<256;i++){
    // -------- phase A: TOut[:,i]=E, build embed window --------
    if(tid < 16){
      int m = tid>>3, kk = tid&7;
      int b = 2*bb + m;
      int p = i - 7 + kk;
      const float* rp = in + b*1792 + p*7;
      float tos = (p == i) ? E_l[m] : toutl[m*256 + p];
      float tmix;
      if(i < 128){
        float ratio = (float)i * 0.0078125f;
        tmix = rp[0]*ratio + tos*(1.f - ratio);
      } else tmix = tos;
      int e = m*EROW + kk*8;
      emb[e+0]=f2bf(tmix); emb[e+1]=f2bf(rp[1]); emb[e+2]=f2bf(rp[2]);
      emb[e+3]=f2bf(rp[3]); emb[e+4]=f2bf(rp[4]);
    }
    if(tid < 2){
      float Ev = E_l[tid];
      toutl[tid*256 + i] = Ev;
      out[(2*bb+tid)*256 + i] = Ev;               // TOut
    }
    __syncthreads();

    // -------- 8 inner LSTM steps --------
    for(int k=0;k<8;k++){
      floatx4 acc[8];
      #pragma unroll
      for(int t=0;t<8;t++){ floatx4 z = {0.f,0.f,0.f,0.f}; acc[t] = z; }
      short8 a[5];
      #pragma unroll
      for(int q=0;q<4;q++) a[q] = *(const short8*)&h_lds[hoff + q*32];
      const unsigned short* p4 = (quad == 0) ? &emb[l15*EROW + k*8] : zpad;
      a[4] = *(const short8*)p4;
      #pragma unroll
      for(int q=0;q<5;q++){
        #pragma unroll
        for(int t=0;t<8;t++)
          acc[t] = __builtin_amdgcn_mfma_f32_16x16x32_bf16(a[q], wfr[t][q], acc[t], 0,0,0);
      }
      if(ln < 16){                                // D: m=quad*4+reg → quad0 regs 0,1 valid
        #pragma unroll
        for(int t=0;t<8;t++){
          int n = 128*(t>>1) + 32*wv + 16*(t&1) + l15;
          gbuf[n]       = acc[t][0];
          gbuf[512 + n] = acc[t][1];
        }
      }
      __syncthreads();
      {                                           // redistributed update: 1/lane
        int m = tid >> 7;
        float gi = gbuf[m*512 +        uj] + bi_i;
        float gf = gbuf[m*512 + 128 + uj] + bi_f;
        float gg = gbuf[m*512 + 256 + uj] + bi_g;
        float go = gbuf[m*512 + 384 + uj] + bi_o;
        c = fast_sig(gf)*c + fast_sig(gi)*fast_tanh(gg);
        float h = fast_sig(go)*fast_tanh(c);
        h_lds[m*HROW + uj] = f2bf(h);
      }
      __syncthreads();
    }

    // -------- fc1 (MFMA, register weights) --------
    {
      floatx4 fa0 = {0.f,0.f,0.f,0.f}, fa1 = fa0;
      short8 a2[4];
      #pragma unroll
      for(int q=0;q<4;q++) a2[q] = *(const short8*)&h_lds[hoff + q*32];
      #pragma unroll
      for(int q=0;q<4;q++){
        fa0 = __builtin_amdgcn_mfma_f32_16x16x32_bf16(a2[q], ffr[0][q], fa0, 0,0,0);
        fa1 = __builtin_amdgcn_mfma_f32_16x16x32_bf16(a2[q], ffr[1][q], fa1, 0,0,0);
      }
      if(ln < 16){
        int n0 = 32*wv + l15, n1 = n0 + 16;
        obuf[n0]       = fmaxf(fa0[0] + fb0, 0.f);
        obuf[128 + n0] = fmaxf(fa0[1] + fb0, 0.f);
        obuf[n1]       = fmaxf(fa1[0] + fb1, 0.f);
        obuf[128 + n1] = fmaxf(fa1[1] + fb1, 0.f);
      }
    }
    __syncthreads();

    // -------- fc2 + E update (waves 0,1 = batch 0,1) --------
    if(wv < 2){
      float v = obuf[wv*128 + ln]*fw0 + obuf[wv*128 + 64 + ln]*fw1;
      #pragma unroll
      for(int off=32; off; off >>= 1) v += __shfl_xor(v, off, 64);
      if(ln == 0){
        int b = 2*bb + wv;
        float ext = v + fc2b0;
        float hv  = in[b*1792 + i*7 + 6];
        float it  = out[3*BT + b*256 + i];
        float total = ext + hv + it;
        float E = E_l[wv];
        if(i < 128){
          float ratio = (float)i * 0.0078125f;
          E = ratio*in[b*1792 + i*7] + (1.f - ratio)*E + total*zw;
        } else {
          E = E + total*zw;
        }
        E_l[wv] = E;
        out[2*BT + b*256 + i] = ext;              // Ext_list
      }
    }
    __syncthreads();
  }
}

extern "C" void kernel_launch(void* const* d_in, const int* in_sizes, int n_in,
                              void* d_out, int out_size, void* d_ws, size_t ws_size,
                              hipStream_t stream)
{
  const float* in   = (const float*)d_in[0];
  const float* Wih  = (const float*)d_in[1];
  const float* Whh  = (const float*)d_in[2];
  const float* bih  = (const float*)d_in[3];
  const float* bhh  = (const float*)d_in[4];
  const float* fc1w = (const float*)d_in[5];
  const float* fc1b = (const float*)d_in[6];
  const float* fc2w = (const float*)d_in[7];
  const float* fc2b = (const float*)d_in[8];
  const float* i1w  = (const float*)d_in[9];
  const float* i1b  = (const float*)d_in[10];
  const float* i3w  = (const float*)d_in[11];
  const float* i3b  = (const float*)d_in[12];
  const float* scw  = (const float*)d_in[13];
  const float* zw   = (const float*)d_in[14];
  float* out = (float*)d_out;

  k_int<<<dim3(512), dim3(256), 0, stream>>>(in, i1w, i1b, i3w, i3b, scw, out);
  k_seq<<<dim3(256), dim3(256), 0, stream>>>(in, Wih, Whh, bih, bhh,
                                             fc1w, fc1b, fc2w, fc2b, zw, out);
}

// Round 2
// 1281.919 us; speedup vs baseline: 1.2706x; 1.2706x over previous
//
#include <hip/hip_runtime.h>

#define BT  (512*256)
#define HROW 168   // h_lds row stride (ushort): 336B = 21*16B, conflict-friendly
#define EROW 8

using short8  = __attribute__((ext_vector_type(8))) short;
using floatx4 = __attribute__((ext_vector_type(4))) float;

__device__ inline unsigned short f2bf(float f){
  unsigned int u = __float_as_uint(f);
  u += 0x7FFFu + ((u >> 16) & 1u);          // RNE
  return (unsigned short)(u >> 16);
}
__device__ inline float fast_sig(float x){
  return __builtin_amdgcn_rcpf(1.f + __expf(-x));
}
__device__ inline float fast_tanh(float x){
  return 1.f - 2.f * __builtin_amdgcn_rcpf(1.f + __expf(2.f * x));
}

// ---------------- kernel 1: int_all + static outputs ----------------
__global__ __launch_bounds__(256) void k_int(
    const float* __restrict__ in, const float* __restrict__ w1,
    const float* __restrict__ b1, const float* __restrict__ w3,
    const float* __restrict__ b3, const float* __restrict__ scw,
    float* __restrict__ out)
{
  __shared__ floatx4 lw[128];
  __shared__ float   l3[128];
  int tid = threadIdx.x;
  if(tid < 128){
    floatx4 v = { w1[tid*3+0], w1[tid*3+1], w1[tid*3+2], b1[tid] };
    lw[tid] = v; l3[tid] = w3[tid];
  }
  __syncthreads();
  int idx = blockIdx.x*256 + tid;
  int b = idx >> 8, t = idx & 255;
  const float* row = in + b*1792 + t*7;
  float x0 = row[3], x1 = row[4], x2 = row[5];
  float acc = 0.f;
  #pragma unroll 8
  for(int j=0;j<128;j++){
    floatx4 w = lw[j];
    float r = fmaxf(w.x*x0 + w.y*x1 + w.z*x2 + w.w, 0.f);
    acc += r * l3[j];
  }
  float v = fast_sig(acc + b3[0]) * scw[0];
  out[idx + BT]   = row[6];                  // HVAC_list
  out[idx + 3*BT] = (t < 8) ? 0.f : v;       // Int_list (also read by k_seq)
  if(t < 8){
    out[idx]        = row[0];                // TOut[:, :8] = T0
    out[idx + 2*BT] = 0.f;                   // Ext_list[:, :8] = 0
  }
}

// ---------------- kernel 2: persistent sequential recurrence ----------------
// 512 threads = 8 waves (2/SIMD). Wave w owns hidden units u = 16w+l15;
// its 4 N-tiles are the 4 gate rows {u, 128+u, 256+u, 384+u} so the gate
// quadruple for each unit lands in ONE quad-0 lane's acc registers.
__global__ __launch_bounds__(512,2) void k_seq(
    const float* __restrict__ in,
    const float* __restrict__ Wih,  const float* __restrict__ Whh,
    const float* __restrict__ bih,  const float* __restrict__ bhh,
    const float* __restrict__ fc1w, const float* __restrict__ fc1b,
    const float* __restrict__ fc2w, const float* __restrict__ fc2b,
    const float* __restrict__ zonew,
    float* __restrict__ out)
{
  __shared__ __align__(16) unsigned short h_lds[2][16*HROW];  // double-buffered h (A-frag rows = batch)
  __shared__ __align__(16) unsigned short emb[16*EROW];       // rows m = b*8+k, cols 0..4 (5..7 = 0)
  __shared__ __align__(16) unsigned short zpad[8];
  __shared__ float xg[8192];        // [k][b][512 gate rows], biases folded in
  __shared__ float obuf[256];       // fc1 relu out, [b][128]
  __shared__ float toutl[512];      // TOut history, [b][256]
  __shared__ float E_l[2], hvit[2], t0i[2];

  const int tid  = threadIdx.x;
  const int wv   = tid >> 6;            // 0..7
  const int ln   = tid & 63;
  const int l15  = ln & 15;
  const int quad = ln >> 4;
  const int bb   = blockIdx.x;          // batches 2*bb, 2*bb+1

  // ---- init LDS ----
  for(int p = tid; p < 2*16*HROW; p += 512) ((unsigned short*)h_lds)[p] = 0;
  for(int p = tid; p < 16*EROW;  p += 512) emb[p] = 0;
  if(tid < 8) zpad[tid] = 0;
  if(tid < 256) h_lds[0][(tid>>7)*HROW + (tid&127)] = 0x3F80;   // h = 1.0
  if(tid < 16) toutl[(tid>>3)*256 + (tid&7)] = in[(2*bb+(tid>>3))*1792 + (tid&7)*7];
  if(tid < 2)  E_l[tid] = in[(2*bb+tid)*1792 + 56];             // E = T0[:,8]

  // ---- weight fragments into VGPRs ----
  short8 wfr[4][4];     // [gate g][K-chunk q], n = 128g + 16wv + l15
  short8 xfr[4];        // W_ih, K=32 pad (5 valid)
  short8 ffr[4];        // fc1, n = 16wv + l15
  float  bsum[4];
  #pragma unroll
  for(int g=0; g<4; g++){
    int n = 128*g + 16*wv + l15;
    bsum[g] = bih[n] + bhh[n];
    #pragma unroll
    for(int q=0; q<4; q++){
      short8 f;
      #pragma unroll
      for(int j=0;j<8;j++) f[j] = (short)f2bf(Whh[n*128 + q*32 + quad*8 + j]);
      wfr[g][q] = f;
    }
    short8 f;
    #pragma unroll
    for(int j=0;j<8;j++){ int kk = quad*8 + j; f[j] = (short)f2bf(kk < 5 ? Wih[n*5 + kk] : 0.f); }
    xfr[g] = f;
  }
  {
    int n = 16*wv + l15;
    #pragma unroll
    for(int q=0; q<4; q++){
      short8 f;
      #pragma unroll
      for(int j=0;j<8;j++) f[j] = (short)f2bf(fc1w[n*128 + q*32 + quad*8 + j]);
      ffr[q] = f;
    }
  }

  const float fb    = fc1b[16*wv + l15];
  const float fw0   = fc2w[ln];
  const float fw1   = fc2w[64 + ln];
  const float fc2b0 = fc2b[0];
  const float zw    = zonew[0];
  const int   u     = 16*wv + l15;          // this lane's hidden unit
  const int   hoff  = l15*HROW + quad*8;    // A-frag base
  const int   b2    = quad & 1;             // batch for update lanes (quad 0,1)
  float c0 = 1.f;                           // cell state (quad<2 lanes)
  __syncthreads();

  #pragma unroll 1
  for(int i=8; i<256; i++){
    // -------- phase A: TOut[:,i]=E, build embed window, prefetch scalars ------
    if(tid < 16){
      int m = tid>>3, kk = tid&7;           // batch m, window pos kk
      int b = 2*bb + m, p = i - 7 + kk;
      const float* rp = in + b*1792 + p*7;
      float tos = (p == i) ? E_l[m] : toutl[m*256 + p];
      float tmix;
      if(i < 128){
        float ratio = (float)i * 0.0078125f;
        tmix = rp[0]*ratio + tos*(1.f - ratio);
      } else tmix = tos;
      int e = (m*8 + kk)*EROW;              // A row = b*8+k
      emb[e+0]=f2bf(tmix); emb[e+1]=f2bf(rp[1]); emb[e+2]=f2bf(rp[2]);
      emb[e+3]=f2bf(rp[3]); emb[e+4]=f2bf(rp[4]);
    }
    if(tid < 2){
      float Ev = E_l[tid];
      toutl[tid*256 + i] = Ev;
      out[(2*bb+tid)*256 + i] = Ev;                                   // TOut
      hvit[tid] = in[(2*bb+tid)*1792 + i*7 + 6] + out[3*BT + (2*bb+tid)*256 + i];
      t0i[tid]  = in[(2*bb+tid)*1792 + i*7];
    }
    __syncthreads();

    // -------- x @ W_ih.T for all 8 inner steps in one MFMA set --------
    {
      short8 ea = (quad == 0) ? *(const short8*)&emb[l15*EROW]
                              : *(const short8*)&zpad[0];
      #pragma unroll
      for(int g=0; g<4; g++){
        floatx4 z = {0.f,0.f,0.f,0.f};
        floatx4 xa = __builtin_amdgcn_mfma_f32_16x16x32_bf16(ea, xfr[g], z, 0,0,0);
        #pragma unroll
        for(int r=0; r<4; r++){
          int mm = quad*4 + r;              // D row = b*8+k
          xg[((mm & 7)*2 + (mm >> 3))*512 + 128*g + u] = xa[r] + bsum[g];
        }
      }
    }
    __syncthreads();

    // -------- 8 inner LSTM steps, ONE barrier each --------
    #pragma unroll 2
    for(int k=0; k<8; k++){
      const unsigned short* hb = h_lds[k & 1];
      short8 a0 = *(const short8*)&hb[hoff];
      short8 a1 = *(const short8*)&hb[hoff + 32];
      short8 a2 = *(const short8*)&hb[hoff + 64];
      short8 a3 = *(const short8*)&hb[hoff + 96];
      float xv0 = xg[(k*2 + b2)*512 +       u];
      float xv1 = xg[(k*2 + b2)*512 + 128 + u];
      float xv2 = xg[(k*2 + b2)*512 + 256 + u];
      float xv3 = xg[(k*2 + b2)*512 + 384 + u];
      floatx4 acc[4];
      #pragma unroll
      for(int g=0; g<4; g++){
        floatx4 z = {0.f,0.f,0.f,0.f};
        z = __builtin_amdgcn_mfma_f32_16x16x32_bf16(a0, wfr[g][0], z, 0,0,0);
        z = __builtin_amdgcn_mfma_f32_16x16x32_bf16(a1, wfr[g][1], z, 0,0,0);
        z = __builtin_amdgcn_mfma_f32_16x16x32_bf16(a2, wfr[g][2], z, 0,0,0);
        z = __builtin_amdgcn_mfma_f32_16x16x32_bf16(a3, wfr[g][3], z, 0,0,0);
        acc[g] = z;
      }
      // spread batch-1 gates (reg 1) from quad0 to quad1
      float s0 = __shfl(acc[0][1], l15, 64);
      float s1 = __shfl(acc[1][1], l15, 64);
      float s2 = __shfl(acc[2][1], l15, 64);
      float s3 = __shfl(acc[3][1], l15, 64);
      if(ln < 32){
        float gi = (quad ? s0 : acc[0][0]) + xv0;
        float gf = (quad ? s1 : acc[1][0]) + xv1;
        float gg = (quad ? s2 : acc[2][0]) + xv2;
        float go = (quad ? s3 : acc[3][0]) + xv3;
        c0 = fast_sig(gf)*c0 + fast_sig(gi)*fast_tanh(gg);
        float hh = fast_sig(go)*fast_tanh(c0);
        h_lds[(k+1) & 1][b2*HROW + u] = f2bf(hh);
      }
      __syncthreads();
    }

    // -------- fc1 (h is in buf 0 after k=7) --------
    {
      const unsigned short* hb = h_lds[0];
      short8 a0 = *(const short8*)&hb[hoff];
      short8 a1 = *(const short8*)&hb[hoff + 32];
      short8 a2 = *(const short8*)&hb[hoff + 64];
      short8 a3 = *(const short8*)&hb[hoff + 96];
      floatx4 fa = {0.f,0.f,0.f,0.f};
      fa = __builtin_amdgcn_mfma_f32_16x16x32_bf16(a0, ffr[0], fa, 0,0,0);
      fa = __builtin_amdgcn_mfma_f32_16x16x32_bf16(a1, ffr[1], fa, 0,0,0);
      fa = __builtin_amdgcn_mfma_f32_16x16x32_bf16(a2, ffr[2], fa, 0,0,0);
      fa = __builtin_amdgcn_mfma_f32_16x16x32_bf16(a3, ffr[3], fa, 0,0,0);
      if(ln < 16){
        obuf[u]       = fmaxf(fa[0] + fb, 0.f);
        obuf[128 + u] = fmaxf(fa[1] + fb, 0.f);
      }
    }
    __syncthreads();

    // -------- fc2 + E update (waves 0,1 = batch 0,1) --------
    if(wv < 2){
      float v = obuf[wv*128 + ln]*fw0 + obuf[wv*128 + 64 + ln]*fw1;
      #pragma unroll
      for(int off=32; off; off >>= 1) v += __shfl_xor(v, off, 64);
      if(ln == 0){
        float ext   = v + fc2b0;
        float total = ext + hvit[wv];
        float E = E_l[wv];
        if(i < 128){
          float ratio = (float)i * 0.0078125f;
          E = ratio*t0i[wv] + (1.f - ratio)*E + total*zw;
        } else {
          E = E + total*zw;
        }
        E_l[wv] = E;
        out[2*BT + (2*bb+wv)*256 + i] = ext;                          // Ext_list
      }
    }
    __syncthreads();
  }
}

extern "C" void kernel_launch(void* const* d_in, const int* in_sizes, int n_in,
                              void* d_out, int out_size, void* d_ws, size_t ws_size,
                              hipStream_t stream)
{
  const float* in   = (const float*)d_in[0];
  const float* Wih  = (const float*)d_in[1];
  const float* Whh  = (const float*)d_in[2];
  const float* bih  = (const float*)d_in[3];
  const float* bhh  = (const float*)d_in[4];
  const float* fc1w = (const float*)d_in[5];
  const float* fc1b = (const float*)d_in[6];
  const float* fc2w = (const float*)d_in[7];
  const float* fc2b = (const float*)d_in[8];
  const float* i1w  = (const float*)d_in[9];
  const float* i1b  = (const float*)d_in[10];
  const float* i3w  = (const float*)d_in[11];
  const float* i3b  = (const float*)d_in[12];
  const float* scw  = (const float*)d_in[13];
  const float* zw   = (const float*)d_in[14];
  float* out = (float*)d_out;

  k_int<<<dim3(512), dim3(256), 0, stream>>>(in, i1w, i1b, i3w, i3b, scw, out);
  k_seq<<<dim3(256), dim3(512), 0, stream>>>(in, Wih, Whh, bih, bhh,
                                             fc1w, fc1b, fc2w, fc2b, zw, out);
}